// Round 3
// baseline (100.999 us; speedup 1.0000x reference)
//
#include <hip/hip_runtime.h>

#define TPB 256
#define PPB 64              // points per block
#define NBLK 2728           // 174592 / 64
#define GNUM 50
#define INF_ 1000000.0f

// Shared pieces of the focal-loss element math, all in terms of a=|x|:
//   e = exp(-a), ln = log(1+e) = softplus(-a), s = 1/(1+e)
//   s2 = s^2 ; apl = a+ln = softplus(a) ; bb = e^2 * ln  (so q^2*ln = s2*bb)
__device__ __forceinline__ void sp_parts(float xx, float& s2, float& apl, float& bb) {
    float a  = fabsf(xx);
    float e  = __expf(-a);
    float t  = 1.0f + e;
    float r  = __builtin_amdgcn_rcpf(t);
    float ln = __logf(t);
    s2  = r * r;
    apl = a + ln;
    bb  = e * e * ln;
}

__global__ __launch_bounds__(TPB) void fcos_fused(
    const float* __restrict__ pred_class,
    const float4* __restrict__ pred_bbox,
    const float* __restrict__ pred_ctr,
    const float4* __restrict__ gt_boxes,
    const int* __restrict__ gt_labels,
    float* __restrict__ partials,
    int* __restrict__ counter,
    float* __restrict__ out)
{
    __shared__ float wpart[4][5];
    __shared__ int lastFlag;

    const int tid = threadIdx.x;
    const int sub = tid & 3;        // 4 lanes cooperate on one point
    const int pt  = tid >> 2;       // local point 0..63
    const int k0  = blockIdx.x << 6;
    const int k   = k0 + pt;

    // ---- issue the 5 coalesced float4 class loads up front (independent) ----
    const float4* pc4 = (const float4*)pred_class + (size_t)blockIdx.x * (PPB * 20);
    float4 v[5];
    #pragma unroll
    for (int it = 0; it < 5; ++it) v[it] = pc4[tid + it * TPB];

    // ---- decode block -> (level, batch, point-base); uniform per block ----
    int li, b, p0;
    if (k0 < 131072)      { li = 0; int r = k0;          b = r >> 14; p0 = r & 16383; }
    else if (k0 < 163840) { li = 1; int r = k0 - 131072; b = r >> 12; p0 = r & 4095; }
    else if (k0 < 172032) { li = 2; int r = k0 - 163840; b = r >> 10; p0 = r & 1023; }
    else if (k0 < 174080) { li = 3; int r = k0 - 172032; b = r >> 8;  p0 = r & 255; }
    else                  { li = 4; int r = k0 - 174080; b = r >> 6;  p0 = r & 63; }

    const int p = p0 + pt;
    const int logn = 7 - li;
    const float sF = (float)(8 << li);
    const float x = ((float)(p & ((1 << logn) - 1)) + 0.5f) * sF;
    const float y = ((float)(p >> logn) + 0.5f) * sF;
    const float lo = (li == 0) ? -1.0f : (float)(64 << (li - 1));
    const float hi = (li == 4) ? INF_ : (float)(64 << li);

    // ---- GT assignment: 4 sub-lanes scan 13 contiguous GTs each ----
    const float4* gb = gt_boxes + b * GNUM;
    float best = INF_;
    int bi = GNUM;
    #pragma unroll
    for (int j = 0; j < 13; ++j) {
        int g = sub * 13 + j;
        int gg = min(g, GNUM - 1);
        float4 bx = gb[gg];
        float l  = x - bx.x;
        float t  = y - bx.y;
        float r  = bx.z - x;
        float bt = bx.w - y;
        float mn = fminf(fminf(l, t), fminf(r, bt));
        float mx = fmaxf(fmaxf(l, t), fmaxf(r, bt));
        float area = (bx.z - bx.x) * (bx.w - bx.y);
        bool ok = (mn > 0.0f) && (mx >= lo) && (mx <= hi) && (g < GNUM);
        float m = ok ? area : INF_;
        if (m < best) { best = m; bi = g; }
    }
    #pragma unroll
    for (int off = 1; off <= 2; off <<= 1) {
        float ob = __shfl_xor(best, off);
        int   oi = __shfl_xor(bi, off);
        if (ob < best || (ob == best && oi < bi)) { best = ob; bi = oi; }
    }

    const bool pos = best < INF_;
    float ctr = 0.0f, lbox = 0.0f, bce = 0.0f, posf = 0.0f, cls = 0.0f;
    if (sub == 0 && pos) {
        posf = 1.0f;
        int lab = gt_labels[b * GNUM + bi] - 1;     // 0..79
        float4 bx = gb[bi];
        float wl = x - bx.x, wt = y - bx.y, wr = bx.z - x, wb = bx.w - y;

        float num = fminf(wl, wr) * fminf(wt, wb);
        float den = fmaxf(wl, wr) * fmaxf(wt, wb) + 1e-12f;
        ctr = sqrtf(fminf(fmaxf(num * __builtin_amdgcn_rcpf(den), 0.0f), 1.0f));

        float4 d = pred_bbox[k];
        float px1 = x - d.x, py1 = y - d.y, px2 = x + d.z, py2 = y + d.w;
        float tx1 = x - wl,  ty1 = y - wt,  tx2 = x + wr,  ty2 = y + wb;
        float ix1 = fmaxf(px1, tx1), iy1 = fmaxf(py1, ty1);
        float ix2 = fminf(px2, tx2), iy2 = fminf(py2, ty2);
        float inter = fmaxf(ix2 - ix1, 0.0f) * fmaxf(iy2 - iy1, 0.0f);
        float ap = fmaxf(px2 - px1, 0.0f) * fmaxf(py2 - py1, 0.0f);
        float at = fmaxf(tx2 - tx1, 0.0f) * fmaxf(ty2 - ty1, 0.0f);
        float iou = inter * __builtin_amdgcn_rcpf(ap + at - inter + 1e-7f);
        lbox = -__logf(fminf(fmaxf(iou, 1e-6f), 1.0f)) * ctr;

        float pc = pred_ctr[k];
        float e  = __expf(-fabsf(pc));
        float l1 = __logf(1.0f + e);
        float sp_p = fmaxf(pc, 0.0f) + l1;
        float sp_n = fmaxf(-pc, 0.0f) + l1;
        bce = ctr * sp_n + (1.0f - ctr) * sp_p;

        // focal-loss correction for the single target element of this point:
        // phase 2 adds 0.75*nontarget for it; true value is 0.25*target.
        float xx = pred_class[(size_t)k * 80 + lab];
        float s2c, aplc, bbc;
        sp_parts(xx, s2c, aplc, bbc);
        float nt = (xx >= 0.0f) ? aplc : bbc;   // nontarget / s^2
        float tg = (xx >= 0.0f) ? bbc : aplc;   // target / s^2
        cls = s2c * fmaf(0.25f, tg, -0.75f * nt);
    }

    // ---- phase 2: non-target focal term for ALL elements (no label lookup) ----
    float acc2 = 0.0f;
    #pragma unroll
    for (int it = 0; it < 5; ++it) {
        float vv[4] = {v[it].x, v[it].y, v[it].z, v[it].w};
        #pragma unroll
        for (int j = 0; j < 4; ++j) {
            float s2, apl, bb;
            sp_parts(vv[j], s2, apl, bb);
            float sel = (vv[j] >= 0.0f) ? apl : bb;
            acc2 = fmaf(s2, sel, acc2);
        }
    }
    cls = fmaf(0.75f, acc2, cls);

    // ---- deterministic block reduction of 5 sums ----
    float v5[5] = {cls, lbox, bce, posf, ctr};
    #pragma unroll
    for (int off = 32; off >= 1; off >>= 1) {
        #pragma unroll
        for (int s2 = 0; s2 < 5; ++s2) v5[s2] += __shfl_down(v5[s2], off);
    }
    const int lane = tid & 63, wid = tid >> 6;
    if (lane == 0) {
        #pragma unroll
        for (int s2 = 0; s2 < 5; ++s2) wpart[wid][s2] = v5[s2];
    }
    __syncthreads();
    if (tid == 0) {
        #pragma unroll
        for (int s2 = 0; s2 < 5; ++s2)
            partials[s2 * NBLK + blockIdx.x] =
                wpart[0][s2] + wpart[1][s2] + wpart[2][s2] + wpart[3][s2];
        __threadfence();                       // release partials (device scope)
        int old = atomicAdd(counter, 1);
        lastFlag = (old == NBLK - 1);
    }
    __syncthreads();

    // ---- last block finalizes (fixed order -> bitwise deterministic) ----
    if (lastFlag) {
        __threadfence();                       // acquire: invalidate caches
        float acc[5] = {0, 0, 0, 0, 0};
        for (int i = tid; i < NBLK; i += TPB) {
            #pragma unroll
            for (int s2 = 0; s2 < 5; ++s2) acc[s2] += partials[s2 * NBLK + i];
        }
        #pragma unroll
        for (int off = 32; off >= 1; off >>= 1) {
            #pragma unroll
            for (int s2 = 0; s2 < 5; ++s2) acc[s2] += __shfl_down(acc[s2], off);
        }
        if (lane == 0) {
            #pragma unroll
            for (int s2 = 0; s2 < 5; ++s2) wpart[wid][s2] = acc[s2];
        }
        __syncthreads();
        if (tid == 0) {
            float S[5];
            #pragma unroll
            for (int s2 = 0; s2 < 5; ++s2)
                S[s2] = wpart[0][s2] + wpart[1][s2] + wpart[2][s2] + wpart[3][s2];
            float pos_num = fmaxf(S[3], 1.0f);
            float denorm  = fmaxf(S[4], 1e-6f);
            out[0] = S[0] / pos_num;
            out[1] = S[1] / denorm;
            out[2] = S[2] / pos_num;
        }
    }
}

extern "C" void kernel_launch(void* const* d_in, const int* in_sizes, int n_in,
                              void* d_out, int out_size, void* d_ws, size_t ws_size,
                              hipStream_t stream) {
    const float*  pred_class = (const float*)d_in[0];
    const float4* pred_bbox  = (const float4*)d_in[1];
    const float*  pred_ctr   = (const float*)d_in[2];
    const float4* gt_boxes   = (const float4*)d_in[3];
    const int*    gt_labels  = (const int*)d_in[4];
    float* partials = (float*)d_ws;                         // 5*NBLK floats
    int*   counter  = (int*)((char*)d_ws + 5 * NBLK * 4);   // 1 int after partials
    float* out = (float*)d_out;

    hipMemsetAsync(counter, 0, 4, stream);                  // graph-capturable
    fcos_fused<<<NBLK, TPB, 0, stream>>>(pred_class, pred_bbox, pred_ctr,
                                         gt_boxes, gt_labels, partials, counter, out);
}

// Round 4
// 31.628 us; speedup vs baseline: 3.1933x; 3.1933x over previous
//
#include <hip/hip_runtime.h>

#define TPB 256
#define PPB 64              // points per block
#define NBLK 2728           // 174592 / 64
#define GNUM 50
#define INF_ 1000000.0f

// Shared pieces of the focal-loss element math, in terms of a=|x|:
//   e = exp(-a), ln = log(1+e) = softplus(-a), s = 1/(1+e)
//   s2 = s^2 ; apl = a+ln = softplus(a) ; bb = e^2 * ln
// non-target term = s2 * (x>=0 ? apl : bb); target term = s2 * (x>=0 ? bb : apl)
__device__ __forceinline__ void sp_parts(float xx, float& s2, float& apl, float& bb) {
    float a  = fabsf(xx);
    float e  = __expf(-a);
    float t  = 1.0f + e;
    float r  = __builtin_amdgcn_rcpf(t);
    float ln = __logf(t);
    s2  = r * r;
    apl = a + ln;
    bb  = e * e * ln;
}

__global__ __launch_bounds__(TPB) void fcos_main(
    const float* __restrict__ pred_class,
    const float4* __restrict__ pred_bbox,
    const float* __restrict__ pred_ctr,
    const float4* __restrict__ gt_boxes,
    const int* __restrict__ gt_labels,
    float* __restrict__ partials)
{
    __shared__ float wpart[4][5];

    const int tid = threadIdx.x;
    const int sub = tid & 3;        // 4 lanes cooperate on one point
    const int pt  = tid >> 2;       // local point 0..63
    const int k0  = blockIdx.x << 6;
    const int k   = k0 + pt;

    // ---- issue the 5 coalesced float4 class loads up front (independent) ----
    const float4* pc4 = (const float4*)pred_class + (size_t)blockIdx.x * (PPB * 20);
    float4 v[5];
    #pragma unroll
    for (int it = 0; it < 5; ++it) v[it] = pc4[tid + it * TPB];

    // ---- decode block -> (level, batch, point-base); uniform per block ----
    int li, b, p0;
    if (k0 < 131072)      { li = 0; int r = k0;          b = r >> 14; p0 = r & 16383; }
    else if (k0 < 163840) { li = 1; int r = k0 - 131072; b = r >> 12; p0 = r & 4095; }
    else if (k0 < 172032) { li = 2; int r = k0 - 163840; b = r >> 10; p0 = r & 1023; }
    else if (k0 < 174080) { li = 3; int r = k0 - 172032; b = r >> 8;  p0 = r & 255; }
    else                  { li = 4; int r = k0 - 174080; b = r >> 6;  p0 = r & 63; }

    const int p = p0 + pt;
    const int logn = 7 - li;
    const float sF = (float)(8 << li);
    const float x = ((float)(p & ((1 << logn) - 1)) + 0.5f) * sF;
    const float y = ((float)(p >> logn) + 0.5f) * sF;
    const float lo = (li == 0) ? -1.0f : (float)(64 << (li - 1));
    const float hi = (li == 4) ? INF_ : (float)(64 << li);

    // ---- GT assignment: 4 sub-lanes scan 13 contiguous GTs each ----
    const float4* gb = gt_boxes + b * GNUM;
    float best = INF_;
    int bi = GNUM;
    #pragma unroll
    for (int j = 0; j < 13; ++j) {
        int g = sub * 13 + j;
        int gg = min(g, GNUM - 1);
        float4 bx = gb[gg];
        float l  = x - bx.x;
        float t  = y - bx.y;
        float r  = bx.z - x;
        float bt = bx.w - y;
        float mn = fminf(fminf(l, t), fminf(r, bt));
        float mx = fmaxf(fmaxf(l, t), fmaxf(r, bt));
        float area = (bx.z - bx.x) * (bx.w - bx.y);
        bool ok = (mn > 0.0f) && (mx >= lo) && (mx <= hi) && (g < GNUM);
        float m = ok ? area : INF_;
        if (m < best) { best = m; bi = g; }
    }
    #pragma unroll
    for (int off = 1; off <= 2; off <<= 1) {
        float ob = __shfl_xor(best, off);
        int   oi = __shfl_xor(bi, off);
        if (ob < best || (ob == best && oi < bi)) { best = ob; bi = oi; }
    }

    const bool pos = best < INF_;
    float ctr = 0.0f, lbox = 0.0f, bce = 0.0f, posf = 0.0f, cls = 0.0f;
    if (sub == 0 && pos) {
        posf = 1.0f;
        int lab = gt_labels[b * GNUM + bi] - 1;     // 0..79
        float4 bx = gb[bi];
        float wl = x - bx.x, wt = y - bx.y, wr = bx.z - x, wb = bx.w - y;

        float num = fminf(wl, wr) * fminf(wt, wb);
        float den = fmaxf(wl, wr) * fmaxf(wt, wb) + 1e-12f;
        ctr = sqrtf(fminf(fmaxf(num * __builtin_amdgcn_rcpf(den), 0.0f), 1.0f));

        float4 d = pred_bbox[k];
        float px1 = x - d.x, py1 = y - d.y, px2 = x + d.z, py2 = y + d.w;
        float tx1 = x - wl,  ty1 = y - wt,  tx2 = x + wr,  ty2 = y + wb;
        float ix1 = fmaxf(px1, tx1), iy1 = fmaxf(py1, ty1);
        float ix2 = fminf(px2, tx2), iy2 = fminf(py2, ty2);
        float inter = fmaxf(ix2 - ix1, 0.0f) * fmaxf(iy2 - iy1, 0.0f);
        float ap = fmaxf(px2 - px1, 0.0f) * fmaxf(py2 - py1, 0.0f);
        float at = fmaxf(tx2 - tx1, 0.0f) * fmaxf(ty2 - ty1, 0.0f);
        float iou = inter * __builtin_amdgcn_rcpf(ap + at - inter + 1e-7f);
        lbox = -__logf(fminf(fmaxf(iou, 1e-6f), 1.0f)) * ctr;

        float pc = pred_ctr[k];
        float e  = __expf(-fabsf(pc));
        float l1 = __logf(1.0f + e);
        float sp_p = fmaxf(pc, 0.0f) + l1;
        float sp_n = fmaxf(-pc, 0.0f) + l1;
        bce = ctr * sp_n + (1.0f - ctr) * sp_p;

        // focal correction for this point's target element:
        // phase 2 adds 0.75*nontarget for it; true value is 0.25*target.
        float xx = pred_class[(size_t)k * 80 + lab];
        float s2c, aplc, bbc;
        sp_parts(xx, s2c, aplc, bbc);
        float nt = (xx >= 0.0f) ? aplc : bbc;
        float tg = (xx >= 0.0f) ? bbc : aplc;
        cls = s2c * fmaf(0.25f, tg, -0.75f * nt);
    }

    // ---- phase 2: non-target focal term for ALL elements (label-free) ----
    float acc2 = 0.0f;
    #pragma unroll
    for (int it = 0; it < 5; ++it) {
        float vv[4] = {v[it].x, v[it].y, v[it].z, v[it].w};
        #pragma unroll
        for (int j = 0; j < 4; ++j) {
            float s2, apl, bb;
            sp_parts(vv[j], s2, apl, bb);
            float sel = (vv[j] >= 0.0f) ? apl : bb;
            acc2 = fmaf(s2, sel, acc2);
        }
    }
    cls = fmaf(0.75f, acc2, cls);

    // ---- deterministic block reduction of 5 sums ----
    float v5[5] = {cls, lbox, bce, posf, ctr};
    #pragma unroll
    for (int off = 32; off >= 1; off >>= 1) {
        #pragma unroll
        for (int s2 = 0; s2 < 5; ++s2) v5[s2] += __shfl_down(v5[s2], off);
    }
    const int lane = tid & 63, wid = tid >> 6;
    if (lane == 0) {
        #pragma unroll
        for (int s2 = 0; s2 < 5; ++s2) wpart[wid][s2] = v5[s2];
    }
    __syncthreads();
    if (tid == 0) {
        #pragma unroll
        for (int s2 = 0; s2 < 5; ++s2)
            partials[s2 * NBLK + blockIdx.x] =
                wpart[0][s2] + wpart[1][s2] + wpart[2][s2] + wpart[3][s2];
    }
}

__global__ __launch_bounds__(TPB) void fcos_final(
    const float* __restrict__ partials, float* __restrict__ out)
{
    const int tid = threadIdx.x;
    float acc[5] = {0, 0, 0, 0, 0};
    for (int i = tid; i < NBLK; i += TPB) {
        #pragma unroll
        for (int s2 = 0; s2 < 5; ++s2) acc[s2] += partials[s2 * NBLK + i];
    }
    #pragma unroll
    for (int off = 32; off >= 1; off >>= 1) {
        #pragma unroll
        for (int s2 = 0; s2 < 5; ++s2) acc[s2] += __shfl_down(acc[s2], off);
    }
    __shared__ float wp[4][5];
    const int lane = tid & 63, wid = tid >> 6;
    if (lane == 0) {
        #pragma unroll
        for (int s2 = 0; s2 < 5; ++s2) wp[wid][s2] = acc[s2];
    }
    __syncthreads();
    if (tid == 0) {
        float S[5];
        #pragma unroll
        for (int s2 = 0; s2 < 5; ++s2)
            S[s2] = wp[0][s2] + wp[1][s2] + wp[2][s2] + wp[3][s2];
        float pos_num = fmaxf(S[3], 1.0f);
        float denorm  = fmaxf(S[4], 1e-6f);
        out[0] = S[0] / pos_num;   // loss_cls
        out[1] = S[1] / denorm;    // loss_box
        out[2] = S[2] / pos_num;   // loss_ctr
    }
}

extern "C" void kernel_launch(void* const* d_in, const int* in_sizes, int n_in,
                              void* d_out, int out_size, void* d_ws, size_t ws_size,
                              hipStream_t stream) {
    const float*  pred_class = (const float*)d_in[0];
    const float4* pred_bbox  = (const float4*)d_in[1];
    const float*  pred_ctr   = (const float*)d_in[2];
    const float4* gt_boxes   = (const float4*)d_in[3];
    const int*    gt_labels  = (const int*)d_in[4];
    float* partials = (float*)d_ws;          // 5 * NBLK floats, fully rewritten each call
    float* out = (float*)d_out;

    fcos_main<<<NBLK, TPB, 0, stream>>>(pred_class, pred_bbox, pred_ctr,
                                        gt_boxes, gt_labels, partials);
    fcos_final<<<1, TPB, 0, stream>>>(partials, out);
}